// Round 4
// baseline (233.244 us; speedup 1.0000x reference)
//
#include <hip/hip_runtime.h>

#define N_NODES 100000
#define DEG 16
#define IN_F 128
#define OUT_F 64
#define E_EDGES (N_NODES * DEG)

typedef __bf16 bf16x8 __attribute__((ext_vector_type(8)));
typedef unsigned short u16x8 __attribute__((ext_vector_type(8)));
typedef float f32x4 __attribute__((ext_vector_type(4)));
typedef unsigned int u32x4 __attribute__((ext_vector_type(4)));

union BF8 { u16x8 u; bf16x8 b; };

__device__ inline float lo_bf(unsigned int u) {
    union { unsigned int i; float f; } v; v.i = u << 16; return v.f;
}
__device__ inline float hi_bf(unsigned int u) {
    union { unsigned int i; float f; } v; v.i = u & 0xFFFF0000u; return v.f;
}
__device__ inline unsigned short f2bf(float f) {
    union { float f; unsigned int i; } v; v.f = f;
    return (unsigned short)((v.i + 0x7FFFu + ((v.i >> 16) & 1u)) >> 16);
}
__device__ inline unsigned int packbf(float a, float b) {
    return (unsigned int)f2bf(a) | ((unsigned int)f2bf(b) << 16);
}

// ---------------- Kernel A: fused W-swizzle + GEMM -> row-major H ----------
// (unchanged from R3 — passed at absmax 0.109)
__global__ __launch_bounds__(256) void k_gemm(
    const float* __restrict__ in, const float* __restrict__ Wh,
    const float* __restrict__ Wl, unsigned int* __restrict__ H)
{
    __shared__ __align__(16) unsigned short ldsW[2][64][136];  // 34816 B
    __shared__ __align__(16) unsigned short ldsA[64][136];     // 17408 B

    {
        int n  = threadIdx.x & 63;          // lane-consecutive -> coalesced
        int kg = threadIdx.x >> 6;          // 4 k-groups of 32
        #pragma unroll
        for (int m = 0; m < 2; m++) {
            const float* W = m ? Wl : Wh;
            #pragma unroll
            for (int i = 0; i < 32; i += 2) {
                int k = kg * 32 + i;
                float a = W[k * 64 + n];
                float b = W[(k + 1) * 64 + n];
                *(unsigned int*)&ldsW[m][n][k] = packbf(a, b);
            }
        }
    }

    int row0B = blockIdx.x * 64;
    {
        const f32x4* src = (const f32x4*)(in + (size_t)row0B * IN_F);
        #pragma unroll
        for (int i = 0; i < 8; i++) {
            int cch = threadIdx.x + 256 * i;
            int row = cch >> 5;
            int kc = (cch & 31) * 4;
            int grow = row0B + row;
            f32x4 v = (grow < N_NODES) ? src[cch]
                      : *(const f32x4*)(in + (size_t)(N_NODES - 1) * IN_F + kc);
            unsigned int p0 = packbf(v[0], v[1]);
            unsigned int p1 = packbf(v[2], v[3]);
            *(unsigned int*)&ldsA[row][kc]     = p0;
            *(unsigned int*)&ldsA[row][kc + 2] = p1;
        }
    }
    __syncthreads();

    int wv = threadIdx.x >> 6;
    int lane = threadIdx.x & 63;
    int quad = lane >> 4, c = lane & 15;
    int row0 = row0B + wv * 16;

    bf16x8 afrag[4];
    #pragma unroll
    for (int kb = 0; kb < 4; kb++) {
        BF8 a;
        a.u = *(const u16x8*)&ldsA[wv * 16 + c][kb * 32 + quad * 8];
        afrag[kb] = a.b;
    }

    f32x4 acc[2][4];
    #pragma unroll
    for (int m = 0; m < 2; m++)
        #pragma unroll
        for (int t = 0; t < 4; t++) acc[m][t] = (f32x4){0, 0, 0, 0};

    #pragma unroll
    for (int kb = 0; kb < 4; kb++) {
        #pragma unroll
        for (int t = 0; t < 4; t++) {
            int n = t * 16 + c;
            BF8 bh, bl;
            bh.u = *(const u16x8*)&ldsW[0][n][kb * 32 + quad * 8];
            bl.u = *(const u16x8*)&ldsW[1][n][kb * 32 + quad * 8];
            acc[0][t] = __builtin_amdgcn_mfma_f32_16x16x32_bf16(afrag[kb], bh.b, acc[0][t], 0, 0, 0);
            acc[1][t] = __builtin_amdgcn_mfma_f32_16x16x32_bf16(afrag[kb], bl.b, acc[1][t], 0, 0, 0);
        }
    }

    #pragma unroll
    for (int r = 0; r < 4; r++) {
        int row = row0 + quad * 4 + r;
        if (row >= N_NODES) continue;
        size_t base = (size_t)row * OUT_F + c;
        #pragma unroll
        for (int t = 0; t < 4; t++)
            H[base + t * 16] = packbf(acc[0][t][r], acc[1][t][r]);
    }
}

// ---------------- Kernel B: HAGG + s, 4-node/wave software pipeline ----------
// Per-node numerics bit-identical to R3 (consume order t=0..15 == half0+half1).
__global__ __launch_bounds__(256) void k_agg(
    const unsigned int* __restrict__ H, const int* __restrict__ dst,
    const float* __restrict__ ah, const float* __restrict__ al,
    unsigned int* __restrict__ HAGG, f32x4* __restrict__ s)
{
    int lane = threadIdx.x & 63;
    int wid = threadIdx.x >> 6;
    int node0 = __builtin_amdgcn_readfirstlane((blockIdx.x * 4 + wid) * 4);

    float a0 = ah[lane], a1 = ah[64 + lane];
    float c0 = al[lane], c1 = al[64 + lane];

    unsigned int g[2][16];
    unsigned int hu[4];

    // prologue: own rows for all 4 nodes + node0's gather batch
    #pragma unroll
    for (int i = 0; i < 4; i++)
        hu[i] = H[(size_t)(node0 + i) * 64 + lane];
    {
        const int* dp = dst + node0 * DEG;
        #pragma unroll
        for (int t = 0; t < 16; t++) {
            int j = dp[t];                         // SGPR
            g[0][t] = H[(size_t)j * 64 + lane];
        }
    }

    #pragma unroll
    for (int i = 0; i < 4; i++) {
        const int cur = i & 1, nxt = cur ^ 1;      // compile-time (unrolled)
        int node = node0 + i;

        if (i < 3) {                               // prefetch node i+1 gathers
            const int* dp = dst + (node + 1) * DEG;
            #pragma unroll
            for (int t = 0; t < 16; t++) {
                int j = dp[t];
                g[nxt][t] = H[(size_t)j * 64 + lane];
            }
        }

        float hh = lo_bf(hu[i]);
        float hl = hi_bf(hu[i]);
        float sh = 16.0f * hh;                     // DEG * h[i] (self-loop)
        float sl = 16.0f * hl;
        #pragma unroll
        for (int t = 0; t < 16; t++) { sh += lo_bf(g[cur][t]); sl -= hi_bf(g[cur][t]); }
        HAGG[(size_t)node * 64 + lane] = packbf(sh, sl);

        float ph = hh * a0;
        float qh = hh * a1;
        float pl = hl * c0;
        float ql = hl * c1;
        #pragma unroll
        for (int o = 32; o > 0; o >>= 1) {
            ph += __shfl_xor(ph, o);
            qh += __shfl_xor(qh, o);
            pl += __shfl_xor(pl, o);
            ql += __shfl_xor(ql, o);
        }
        if (lane == 0) s[node] = (f32x4){ph, qh, pl, ql};
    }
}

// ---------------- Kernel C: weighted aggregate, 4-node/wave pipeline ----------
// Per-node numerics bit-identical to R3.
__global__ __launch_bounds__(256) void k_out(
    const unsigned int* __restrict__ HAGG, const int* __restrict__ dst,
    const f32x4* __restrict__ s, float* __restrict__ out)
{
    int lane = threadIdx.x & 63;
    int wid = threadIdx.x >> 6;
    int node0 = __builtin_amdgcn_readfirstlane((blockIdx.x * 4 + wid) * 4);

    unsigned int g[2][16];
    f32x4 sjv[2];

    // prologue: node0's s-gather + HAGG gather batch
    {
        const int* dp = dst + node0 * DEG;
        int jl = dp[lane & 15];
        sjv[0] = s[jl];
        #pragma unroll
        for (int t = 0; t < 16; t++) {
            int j = dp[t];                          // SGPR
            g[0][t] = HAGG[(size_t)j * 64 + lane];
        }
    }

    #pragma unroll
    for (int i = 0; i < 4; i++) {
        const int cur = i & 1, nxt = cur ^ 1;       // compile-time (unrolled)
        int node = node0 + i;

        if (i < 3) {                                // prefetch node i+1
            const int* dp = dst + (node + 1) * DEG;
            int jl = dp[lane & 15];
            sjv[nxt] = s[jl];
            #pragma unroll
            for (int t = 0; t < 16; t++) {
                int j = dp[t];
                g[nxt][t] = HAGG[(size_t)j * 64 + lane];
            }
        }

        f32x4 si = s[node];                         // wave-uniform (scalar)
        f32x4 sj = sjv[cur];
        float xh = si.x + sj.y;                     // p_high[i] + q_high[j]
        float xl = si.z + sj.w;
        float lh = xh > 0.0f ? xh : 0.2f * xh;
        float ll = xl > 0.0f ? xl : 0.2f * xl;
        float wh = __expf(-lh);
        float wl = __expf(-ll);
        float rh = wh, rl = wl;                     // rowsum over RAW exp values
        #pragma unroll
        for (int o = 8; o > 0; o >>= 1) { rh += __shfl_xor(rh, o); rl += __shfl_xor(rl, o); }
        float eh = fminf(wh, 6.0f);                 // relu6 on weights
        float el = fminf(wl, 6.0f);

        float acc_h = 0.0f, acc_l = 0.0f;
        #pragma unroll
        for (int t = 0; t < 16; t++) {
            float weh = __shfl(eh, t);
            float wel = __shfl(el, t);
            acc_h += weh * lo_bf(g[cur][t]);
            acc_l += wel * hi_bf(g[cur][t]);
        }
        float r = 0.5f * (acc_h / rh + acc_l / rl);
        r = fminf(fmaxf(r, 0.0f), 6.0f);
        out[(size_t)node * 64 + lane] = r;
    }
}

extern "C" void kernel_launch(void* const* d_in, const int* in_sizes, int n_in,
                              void* d_out, int out_size, void* d_ws, size_t ws_size,
                              hipStream_t stream) {
    const float* input = (const float*)d_in[0];
    const int*   edge  = (const int*)d_in[1];     // [2, E]: src then dst
    const float* Wh    = (const float*)d_in[2];
    const float* Wl    = (const float*)d_in[3];
    const float* ah    = (const float*)d_in[4];
    const float* al    = (const float*)d_in[5];
    float* out = (float*)d_out;

    unsigned int* H    = (unsigned int*)d_ws;                    // 25.6 MB
    unsigned int* HAGG = H + (size_t)N_NODES * 64;               // 25.6 MB
    f32x4* s = (f32x4*)(HAGG + (size_t)N_NODES * 64);            // 1.6 MB

    const int* dstp = edge + E_EDGES;

    k_gemm<<<1563, 256, 0, stream>>>(input, Wh, Wl, H);
    k_agg<<<N_NODES / 16, 256, 0, stream>>>(H, dstp, ah, al, HAGG, s);
    k_out<<<N_NODES / 16, 256, 0, stream>>>(HAGG, dstp, s, out);
}

// Round 5
// 225.840 us; speedup vs baseline: 1.0328x; 1.0328x over previous
//
#include <hip/hip_runtime.h>

#define N_NODES 100000
#define DEG 16
#define IN_F 128
#define OUT_F 64
#define E_EDGES (N_NODES * DEG)
#define TILES 1563          // ceil(N_NODES / 64)
#define GEMM_GRID 768       // 3 blocks/CU (52 KB LDS) x 256 CUs

typedef __bf16 bf16x8 __attribute__((ext_vector_type(8)));
typedef unsigned short u16x8 __attribute__((ext_vector_type(8)));
typedef float f32x4 __attribute__((ext_vector_type(4)));
typedef unsigned int u32x4 __attribute__((ext_vector_type(4)));

union BF8 { u16x8 u; bf16x8 b; };

__device__ inline float lo_bf(unsigned int u) {
    union { unsigned int i; float f; } v; v.i = u << 16; return v.f;
}
__device__ inline float hi_bf(unsigned int u) {
    union { unsigned int i; float f; } v; v.i = u & 0xFFFF0000u; return v.f;
}
__device__ inline unsigned short f2bf(float f) {
    union { float f; unsigned int i; } v; v.f = f;
    return (unsigned short)((v.i + 0x7FFFu + ((v.i >> 16) & 1u)) >> 16);
}
__device__ inline unsigned int packbf(float a, float b) {
    return (unsigned int)f2bf(a) | ((unsigned int)f2bf(b) << 16);
}

// ---------------- Kernel A: persistent-block W-swizzle + pipelined GEMM ----
// ldsW built ONCE per block (768 blocks vs 1563); tiles grid-strided with a
// register->LDS stage pipeline: tile t+1's global loads issue during tile t's
// MFMA phase. Per-tile numerics bit-identical to R3.
__global__ __launch_bounds__(256) void k_gemm(
    const float* __restrict__ in, const float* __restrict__ Wh,
    const float* __restrict__ Wl, unsigned int* __restrict__ H)
{
    __shared__ __align__(16) unsigned short ldsW[2][64][136];  // 34816 B
    __shared__ __align__(16) unsigned short ldsA[64][136];     // 17408 B

    // W conversion: coalesced 256-B reads along n; packed u32 LDS writes.
    {
        int n  = threadIdx.x & 63;          // lane-consecutive -> coalesced
        int kg = threadIdx.x >> 6;          // 4 k-groups of 32
        #pragma unroll
        for (int m = 0; m < 2; m++) {
            const float* W = m ? Wl : Wh;
            #pragma unroll
            for (int i = 0; i < 32; i += 2) {
                int k = kg * 32 + i;
                float a = W[k * 64 + n];
                float b = W[(k + 1) * 64 + n];
                *(unsigned int*)&ldsW[m][n][k] = packbf(a, b);
            }
        }
    }

    int wv = threadIdx.x >> 6;
    int lane = threadIdx.x & 63;
    int quad = lane >> 4, c = lane & 15;

    f32x4 av[8];
    int tile = blockIdx.x;
    if (tile >= TILES) return;

    // prologue: load first tile's A rows into registers
    {
        int row0B = tile * 64;
        const f32x4* src = (const f32x4*)(in + (size_t)row0B * IN_F);
        #pragma unroll
        for (int i = 0; i < 8; i++) {
            int cch = threadIdx.x + 256 * i;     // 2048 chunks of f32x4
            int row = cch >> 5;                  // 32 chunks per row
            int kc = (cch & 31) * 4;
            int grow = row0B + row;
            av[i] = (grow < N_NODES) ? src[cch]
                    : *(const f32x4*)(in + (size_t)(N_NODES - 1) * IN_F + kc);
        }
    }

    for (; tile < TILES; tile += GEMM_GRID) {
        int row0B = tile * 64;

        __syncthreads();   // prev tile's LDS reads done (also orders ldsW once)
        #pragma unroll
        for (int i = 0; i < 8; i++) {
            int cch = threadIdx.x + 256 * i;
            int row = cch >> 5;
            int kc = (cch & 31) * 4;
            *(unsigned int*)&ldsA[row][kc]     = packbf(av[i][0], av[i][1]);
            *(unsigned int*)&ldsA[row][kc + 2] = packbf(av[i][2], av[i][3]);
        }
        __syncthreads();

        // prefetch next tile while this tile computes (block-uniform branch)
        int ntile = tile + GEMM_GRID;
        if (ntile < TILES) {
            int nrow0 = ntile * 64;
            const f32x4* src = (const f32x4*)(in + (size_t)nrow0 * IN_F);
            #pragma unroll
            for (int i = 0; i < 8; i++) {
                int cch = threadIdx.x + 256 * i;
                int row = cch >> 5;
                int kc = (cch & 31) * 4;
                int grow = nrow0 + row;
                av[i] = (grow < N_NODES) ? src[cch]
                        : *(const f32x4*)(in + (size_t)(N_NODES - 1) * IN_F + kc);
            }
        }

        bf16x8 afrag[4];
        #pragma unroll
        for (int kb = 0; kb < 4; kb++) {
            BF8 a;
            a.u = *(const u16x8*)&ldsA[wv * 16 + c][kb * 32 + quad * 8];
            afrag[kb] = a.b;
        }

        f32x4 acc[2][4];
        #pragma unroll
        for (int m = 0; m < 2; m++)
            #pragma unroll
            for (int t = 0; t < 4; t++) acc[m][t] = (f32x4){0, 0, 0, 0};

        #pragma unroll
        for (int kb = 0; kb < 4; kb++) {
            #pragma unroll
            for (int t = 0; t < 4; t++) {
                int n = t * 16 + c;
                BF8 bh, bl;
                bh.u = *(const u16x8*)&ldsW[0][n][kb * 32 + quad * 8];
                bl.u = *(const u16x8*)&ldsW[1][n][kb * 32 + quad * 8];
                acc[0][t] = __builtin_amdgcn_mfma_f32_16x16x32_bf16(afrag[kb], bh.b, acc[0][t], 0, 0, 0);
                acc[1][t] = __builtin_amdgcn_mfma_f32_16x16x32_bf16(afrag[kb], bl.b, acc[1][t], 0, 0, 0);
            }
        }

        // C/D: col = t*16 + c, row = quad*4 + r  (proven mapping)
        int row0 = row0B + wv * 16;
        #pragma unroll
        for (int r = 0; r < 4; r++) {
            int row = row0 + quad * 4 + r;
            if (row >= N_NODES) continue;
            size_t base = (size_t)row * OUT_F + c;
            #pragma unroll
            for (int t = 0; t < 4; t++)
                H[base + t * 16] = packbf(acc[0][t][r], acc[1][t][r]);
        }
    }
}

// ---------------- Kernel B: HAGG + attention scalars s (R3 verbatim) ----
__global__ __launch_bounds__(256) void k_agg(
    const unsigned int* __restrict__ H, const int* __restrict__ dst,
    const float* __restrict__ ah, const float* __restrict__ al,
    unsigned int* __restrict__ HAGG, f32x4* __restrict__ s)
{
    int lane = threadIdx.x & 63;
    int node = __builtin_amdgcn_readfirstlane(blockIdx.x * 4 + (threadIdx.x >> 6));
    const int* dp = dst + node * DEG;   // 64-B aligned row, scalar loads

    unsigned int hu = H[(size_t)node * 64 + lane];
    float hh = lo_bf(hu);
    float hl = hi_bf(hu);
    float sh = 16.0f * hh;   // DEG * h[i] (self-loop among the 16 dst)
    float sl = 16.0f * hl;

    #pragma unroll
    for (int half = 0; half < 2; half++) {
        unsigned int u[8];
        #pragma unroll
        for (int t = 0; t < 8; t++) {
            int j = dp[half * 8 + t];                 // SGPR
            u[t] = H[(size_t)j * 64 + lane];          // 8 independent loads in flight
        }
        #pragma unroll
        for (int t = 0; t < 8; t++) { sh += lo_bf(u[t]); sl -= hi_bf(u[t]); }
    }
    HAGG[(size_t)node * 64 + lane] = packbf(sh, sl);

    float ph = hh * ah[lane];
    float qh = hh * ah[64 + lane];
    float pl = hl * al[lane];
    float ql = hl * al[64 + lane];
    #pragma unroll
    for (int o = 32; o > 0; o >>= 1) {
        ph += __shfl_xor(ph, o);
        qh += __shfl_xor(qh, o);
        pl += __shfl_xor(pl, o);
        ql += __shfl_xor(ql, o);
    }
    if (lane == 0) s[node] = (f32x4){ph, qh, pl, ql};
}

// ---------------- Kernel C: weighted aggregate + relu6 (R3 verbatim) ----
__global__ __launch_bounds__(256) void k_out(
    const unsigned int* __restrict__ HAGG, const int* __restrict__ dst,
    const f32x4* __restrict__ s, float* __restrict__ out)
{
    int lane = threadIdx.x & 63;
    int node = __builtin_amdgcn_readfirstlane(blockIdx.x * 4 + (threadIdx.x >> 6));
    const int* dp = dst + node * DEG;

    int jl = dp[lane & 15];                   // lane e<16 owns edge e
    f32x4 si = s[node];                       // wave-uniform
    f32x4 sj = s[jl];
    float xh = si.x + sj.y;                   // p_high[i] + q_high[j]
    float xl = si.z + sj.w;
    float lh = xh > 0.0f ? xh : 0.2f * xh;
    float ll = xl > 0.0f ? xl : 0.2f * xl;
    float wh = __expf(-lh);
    float wl = __expf(-ll);
    float rh = wh, rl = wl;                   // rowsum over RAW exp values
    #pragma unroll
    for (int o = 8; o > 0; o >>= 1) { rh += __shfl_xor(rh, o); rl += __shfl_xor(rl, o); }
    float eh = fminf(wh, 6.0f);               // relu6 on weights
    float el = fminf(wl, 6.0f);

    float acc_h = 0.0f, acc_l = 0.0f;
    #pragma unroll
    for (int half = 0; half < 2; half++) {
        unsigned int u[8];
        float weh[8], wel[8];
        #pragma unroll
        for (int t = 0; t < 8; t++) {
            int j = dp[half * 8 + t];                 // SGPR
            u[t] = HAGG[(size_t)j * 64 + lane];       // 8 independent loads in flight
        }
        #pragma unroll
        for (int t = 0; t < 8; t++) {
            weh[t] = __shfl(eh, half * 8 + t);
            wel[t] = __shfl(el, half * 8 + t);
        }
        #pragma unroll
        for (int t = 0; t < 8; t++) {
            acc_h += weh[t] * lo_bf(u[t]);
            acc_l += wel[t] * hi_bf(u[t]);
        }
    }
    float r = 0.5f * (acc_h / rh + acc_l / rl);
    r = fminf(fmaxf(r, 0.0f), 6.0f);
    out[(size_t)node * 64 + lane] = r;
}

extern "C" void kernel_launch(void* const* d_in, const int* in_sizes, int n_in,
                              void* d_out, int out_size, void* d_ws, size_t ws_size,
                              hipStream_t stream) {
    const float* input = (const float*)d_in[0];
    const int*   edge  = (const int*)d_in[1];     // [2, E]: src then dst
    const float* Wh    = (const float*)d_in[2];
    const float* Wl    = (const float*)d_in[3];
    const float* ah    = (const float*)d_in[4];
    const float* al    = (const float*)d_in[5];
    float* out = (float*)d_out;

    unsigned int* H    = (unsigned int*)d_ws;                    // 25.6 MB
    unsigned int* HAGG = H + (size_t)N_NODES * 64;               // 25.6 MB
    f32x4* s = (f32x4*)(HAGG + (size_t)N_NODES * 64);            // 1.6 MB

    const int* dstp = edge + E_EDGES;

    k_gemm<<<GEMM_GRID, 256, 0, stream>>>(input, Wh, Wl, H);
    k_agg<<<N_NODES / 4, 256, 0, stream>>>(H, dstp, ah, al, HAGG, s);
    k_out<<<N_NODES / 4, 256, 0, stream>>>(HAGG, dstp, s, out);
}